// Round 2
// baseline (961.913 us; speedup 1.0000x reference)
//
#include <hip/hip_runtime.h>
#include <hip/hip_bf16.h>
#include <cstdint>
#include <cstddef>

// Problem constants (B*F tokens)
#define T_TOK 8192
#define DDIM  1024
#define HDIM  2048
#define NEXP  8
#define TOPK  2
#define KAUG  (3 * DDIM)   // split-bf16 router K

typedef short bf16x8 __attribute__((ext_vector_type(8)));
typedef float f32x4  __attribute__((ext_vector_type(4)));

__device__ __forceinline__ unsigned short f2bf(float f) {
  union { float f; unsigned u; } v; v.f = f;
  unsigned r = v.u + 0x7FFFu + ((v.u >> 16) & 1u);
  return (unsigned short)(r >> 16);
}
__device__ __forceinline__ float bf2f(unsigned short h) {
  union { unsigned u; float f; } v; v.u = ((unsigned)h) << 16;
  return v.f;
}
__device__ __forceinline__ float silu_fast(float v) {
  return v / (1.0f + __expf(-v));
}
__device__ __forceinline__ float silu_precise(float v) {
  return v / (1.0f + expf(-v));
}

// ---------------- conversion kernels ----------------
// x fp32 -> xb (bf16 hi) and xaug = [hi | hi | lo] per row (K=3072)
__global__ void split_x_kernel(const float* __restrict__ in,
                               unsigned short* __restrict__ xb,
                               unsigned short* __restrict__ xaug, int n4) {
  int i = blockIdx.x * blockDim.x + threadIdx.x;
  if (i >= n4) return;
  float4 v = ((const float4*)in)[i];
  int t = i / (DDIM / 4);
  int kc = (i % (DDIM / 4)) * 4;
  float f[4] = {v.x, v.y, v.z, v.w};
  ushort4 hi, lo;
  unsigned short h[4], l[4];
#pragma unroll
  for (int j = 0; j < 4; j++) {
    h[j] = f2bf(f[j]);
    l[j] = f2bf(f[j] - bf2f(h[j]));
  }
  hi.x = h[0]; hi.y = h[1]; hi.z = h[2]; hi.w = h[3];
  lo.x = l[0]; lo.y = l[1]; lo.z = l[2]; lo.w = l[3];
  *(ushort4*)&xb[(size_t)t * DDIM + kc] = hi;
  *(ushort4*)&xaug[(size_t)t * KAUG + kc] = hi;
  *(ushort4*)&xaug[(size_t)t * KAUG + DDIM + kc] = hi;
  *(ushort4*)&xaug[(size_t)t * KAUG + 2 * DDIM + kc] = lo;
}

// rw1 [k][n] fp32 -> waug [n][3072] = [whi | wlo | whi]
__global__ __launch_bounds__(256) void split_w_kernel(
    const float* __restrict__ in, unsigned short* __restrict__ waug) {
  __shared__ float tile[32][33];
  int c0 = blockIdx.x * 32, r0 = blockIdx.y * 32;
  int tx = threadIdx.x & 31, ty = threadIdx.x >> 5;
#pragma unroll
  for (int i = 0; i < 32; i += 8)
    tile[ty + i][tx] = in[(size_t)(r0 + ty + i) * DDIM + (c0 + tx)];
  __syncthreads();
#pragma unroll
  for (int i = 0; i < 32; i += 8) {
    float v = tile[tx][ty + i];          // in[r0+tx][c0+ty+i]
    unsigned short h = f2bf(v);
    unsigned short l = f2bf(v - bf2f(h));
    int n = c0 + ty + i, k = r0 + tx;
    waug[(size_t)n * KAUG + k] = h;
    waug[(size_t)n * KAUG + DDIM + k] = l;
    waug[(size_t)n * KAUG + 2 * DDIM + k] = h;
  }
}

// in: [z][R][C] fp32 -> out: [z][C][R] bf16
__global__ __launch_bounds__(256) void transpose_conv_kernel(
    const float* __restrict__ in, unsigned short* __restrict__ out, int R, int C) {
  __shared__ float tile[32][33];
  const int z = blockIdx.z;
  const float* src = in + (size_t)z * R * C;
  unsigned short* dst = out + (size_t)z * R * C;
  int c0 = blockIdx.x * 32, r0 = blockIdx.y * 32;
  int tx = threadIdx.x & 31, ty = threadIdx.x >> 5;
#pragma unroll
  for (int i = 0; i < 32; i += 8)
    tile[ty + i][tx] = src[(size_t)(r0 + ty + i) * C + (c0 + tx)];
  __syncthreads();
#pragma unroll
  for (int i = 0; i < 32; i += 8)
    dst[(size_t)(c0 + ty + i) * R + (r0 + tx)] = f2bf(tile[tx][ty + i]);
}

__global__ void copy_x_kernel(const float* __restrict__ x,
                              float* __restrict__ y, int n4) {
  int i = blockIdx.x * blockDim.x + threadIdx.x;
  if (i < n4) ((float4*)y)[i] = ((const float4*)x)[i];
}

__global__ void zero_small_kernel(int* __restrict__ counts, int* __restrict__ cursors) {
  int i = threadIdx.x;
  if (i < NEXP) { counts[i] = 0; cursors[i] = 0; }
}

// ---------------- MFMA GEMM (128x128 tile, BK=32, 4 waves) ----------------
// EPI=0: router1  -> outF[p*N+col] = silu(acc + bias[col])          (A dense)
// EPI=1: expert1  -> outBf[(off+p)*N+col] = bf16(silu(acc+bias))    (A gathered by toks)
// EPI=2: expert2  -> atomicAdd(outF[tok*N+col], w*(acc+bias))       (A = packed ehb)
template <int EPI>
__global__ __launch_bounds__(256) void gemm_mfma(
    const unsigned short* __restrict__ Abase,
    const unsigned short* __restrict__ Btbase,  // [z][N][KD] bf16 (pre-transposed)
    const float* __restrict__ bias,             // [z][N]
    float* __restrict__ outF,
    unsigned short* __restrict__ outBf,
    const int* __restrict__ toks, const float* __restrict__ wts,
    const int* __restrict__ offs, const int* __restrict__ cnts,
    int N, int KD) {
  const int e = blockIdx.z;
  int ne = 1 << 30, off = 0;
  if (EPI != 0) { ne = cnts[e]; off = offs[e]; }
  const int m0 = blockIdx.x * 128;
  if (EPI != 0 && m0 >= ne) return;
  const int n0 = blockIdx.y * 128;

  const unsigned short* Bt = Btbase + (size_t)e * N * KD;
  const unsigned short* A = (EPI == 2) ? (Abase + (size_t)off * KD) : Abase;

  __shared__ unsigned short As[128][32];
  __shared__ unsigned short Bs[128][32];

  const int tid  = threadIdx.x;
  const int lane = tid & 63, wid = tid >> 6;
  const int wm = wid >> 1, wn = wid & 1;
  const int quad = lane >> 4, l16 = lane & 15;

  // staging map: each thread loads 2x 16B for A and 2x 16B for B
  const int rowS0 = tid >> 2, rowS1 = (tid >> 2) + 64;
  const int kc0 = (tid & 3) * 8;

  size_t arow0, arow1;
  if (EPI == 1) {
    int p0 = m0 + rowS0, p1 = m0 + rowS1;
    int t0 = (p0 < ne) ? toks[off + p0] : 0;
    int t1 = (p1 < ne) ? toks[off + p1] : 0;
    arow0 = (size_t)t0 * KD;
    arow1 = (size_t)t1 * KD;
  } else if (EPI == 2) {
    int p0 = min(m0 + rowS0, ne - 1);
    int p1 = min(m0 + rowS1, ne - 1);
    arow0 = (size_t)p0 * KD;
    arow1 = (size_t)p1 * KD;
  } else {
    arow0 = (size_t)(m0 + rowS0) * KD;
    arow1 = (size_t)(m0 + rowS1) * KD;
  }
  const size_t brow0 = (size_t)(n0 + rowS0) * KD;
  const size_t brow1 = (size_t)(n0 + rowS1) * KD;

  f32x4 zf = {0.f, 0.f, 0.f, 0.f};
  f32x4 acc[4][4];
#pragma unroll
  for (int mi = 0; mi < 4; mi++)
#pragma unroll
    for (int ni = 0; ni < 4; ni++) acc[mi][ni] = zf;

  for (int k0 = 0; k0 < KD; k0 += 32) {
    *(bf16x8*)&As[rowS0][kc0] = *(const bf16x8*)(A + arow0 + k0 + kc0);
    *(bf16x8*)&As[rowS1][kc0] = *(const bf16x8*)(A + arow1 + k0 + kc0);
    *(bf16x8*)&Bs[rowS0][kc0] = *(const bf16x8*)(Bt + brow0 + k0 + kc0);
    *(bf16x8*)&Bs[rowS1][kc0] = *(const bf16x8*)(Bt + brow1 + k0 + kc0);
    __syncthreads();
    bf16x8 af[4], bfr[4];
#pragma unroll
    for (int mi = 0; mi < 4; mi++)
      af[mi] = *(const bf16x8*)&As[wm * 64 + mi * 16 + l16][quad * 8];
#pragma unroll
    for (int ni = 0; ni < 4; ni++)
      bfr[ni] = *(const bf16x8*)&Bs[wn * 64 + ni * 16 + l16][quad * 8];
#pragma unroll
    for (int mi = 0; mi < 4; mi++)
#pragma unroll
      for (int ni = 0; ni < 4; ni++)
        acc[mi][ni] = __builtin_amdgcn_mfma_f32_16x16x32_bf16(
            af[mi], bfr[ni], acc[mi][ni], 0, 0, 0);
    __syncthreads();
  }

  // epilogue (C/D layout: col = lane&15, row = quad*4 + r)
#pragma unroll
  for (int mi = 0; mi < 4; mi++) {
    const int prow_base = wm * 64 + mi * 16 + quad * 4;
#pragma unroll
    for (int r = 0; r < 4; r++) {
      const int p = m0 + prow_base + r;
      if (EPI != 0 && p >= ne) continue;
      int tkn = 0; float wgt = 0.f;
      if (EPI == 2) { tkn = toks[off + p]; wgt = wts[off + p]; }
#pragma unroll
      for (int ni = 0; ni < 4; ni++) {
        const int col = n0 + wn * 64 + ni * 16 + l16;
        float v = acc[mi][ni][r] + bias[(size_t)e * N + col];
        if (EPI == 0) {
          outF[(size_t)p * N + col] = silu_precise(v);
        } else if (EPI == 1) {
          outBf[(size_t)(off + p) * N + col] = f2bf(silu_fast(v));
        } else {
          atomicAdd(&outF[(size_t)tkn * N + col], wgt * v);
        }
      }
    }
  }
}

// ---------------- router second layer: logits = rh @ rw2 + rb2 ----------------
__global__ __launch_bounds__(256) void router2_kernel(
    const float* __restrict__ rh, const float* __restrict__ rw2,
    const float* __restrict__ rb2, float* __restrict__ logits) {
  int t = blockIdx.x * 4 + (threadIdx.x >> 6);
  int lane = threadIdx.x & 63;
  const float* row = rh + (size_t)t * DDIM;
  float acc[NEXP];
#pragma unroll
  for (int e = 0; e < NEXP; e++) acc[e] = 0.f;
  for (int k = lane; k < DDIM; k += 64) {
    float v = row[k];
    const float* w = rw2 + (size_t)k * NEXP;
#pragma unroll
    for (int e = 0; e < NEXP; e++) acc[e] += v * w[e];
  }
#pragma unroll
  for (int e = 0; e < NEXP; e++) {
#pragma unroll
    for (int off = 32; off > 0; off >>= 1) acc[e] += __shfl_xor(acc[e], off, 64);
  }
#pragma unroll
  for (int e = 0; e < NEXP; e++)
    if (lane == e) logits[(size_t)t * NEXP + e] = acc[e] + rb2[e];
}

// ---------------- top-2 + softmax + counts ----------------
__global__ void topk_kernel(const float* __restrict__ logits,
                            int* __restrict__ idx2, float* __restrict__ w2arr,
                            int* __restrict__ counts) {
  int t = blockIdx.x * blockDim.x + threadIdx.x;
  if (t >= T_TOK) return;
  float l[NEXP];
#pragma unroll
  for (int e = 0; e < NEXP; e++) l[e] = logits[(size_t)t * NEXP + e];
  int i1 = 0; float v1 = l[0];
#pragma unroll
  for (int e = 1; e < NEXP; e++)
    if (l[e] > v1) { v1 = l[e]; i1 = e; }
  int i2 = -1; float v2 = -3.4e38f;
#pragma unroll
  for (int e = 0; e < NEXP; e++)
    if (e != i1 && l[e] > v2) { v2 = l[e]; i2 = e; }
  float ex = expf(v2 - v1);
  float wa = 1.f / (1.f + ex);
  float wb = ex / (1.f + ex);
  idx2[t * 2] = i1; idx2[t * 2 + 1] = i2;
  w2arr[t * 2] = wa; w2arr[t * 2 + 1] = wb;
  atomicAdd(&counts[i1], 1);
  atomicAdd(&counts[i2], 1);
}

__global__ void prefix_kernel(const int* __restrict__ counts, int* __restrict__ offs) {
  if (threadIdx.x == 0 && blockIdx.x == 0) {
    int s = 0;
    for (int e = 0; e < NEXP; e++) { offs[e] = s; s += counts[e]; }
  }
}

__global__ void scatter_kernel(const int* __restrict__ idx2,
                               const float* __restrict__ w2arr,
                               const int* __restrict__ offs, int* __restrict__ cursors,
                               int* __restrict__ toks, float* __restrict__ wts) {
  int t = blockIdx.x * blockDim.x + threadIdx.x;
  if (t >= T_TOK) return;
#pragma unroll
  for (int j = 0; j < TOPK; j++) {
    int e = idx2[t * 2 + j];
    int pos = atomicAdd(&cursors[e], 1);
    int s = offs[e] + pos;
    toks[s] = t;
    wts[s] = w2arr[t * 2 + j];
  }
}

// ---------------- launch ----------------
extern "C" void kernel_launch(void* const* d_in, const int* in_sizes, int n_in,
                              void* d_out, int out_size, void* d_ws, size_t ws_size,
                              hipStream_t stream) {
  (void)in_sizes; (void)n_in; (void)out_size; (void)ws_size;
  const float* x   = (const float*)d_in[0];
  const float* rw1 = (const float*)d_in[1];
  const float* rb1 = (const float*)d_in[2];
  const float* rw2 = (const float*)d_in[3];
  const float* rb2 = (const float*)d_in[4];
  const float* ew1 = (const float*)d_in[5];
  const float* eb1 = (const float*)d_in[6];
  const float* ew2 = (const float*)d_in[7];
  const float* eb2 = (const float*)d_in[8];
  float* y = (float*)d_out;

  char* ws = (char*)d_ws;
  size_t o = 0;
  auto alloc = [&](size_t bytes) {
    size_t r = o;
    o += (bytes + 255) & ~(size_t)255;
    return r;
  };
  unsigned short* xb    = (unsigned short*)(ws + alloc((size_t)T_TOK * DDIM * 2));
  unsigned short* xaug  = (unsigned short*)(ws + alloc((size_t)T_TOK * KAUG * 2));
  unsigned short* waug  = (unsigned short*)(ws + alloc((size_t)DDIM * KAUG * 2));
  unsigned short* ew1t  = (unsigned short*)(ws + alloc((size_t)NEXP * HDIM * DDIM * 2));
  unsigned short* ew2t  = (unsigned short*)(ws + alloc((size_t)NEXP * DDIM * HDIM * 2));
  float*          rh    = (float*)(ws + alloc((size_t)T_TOK * DDIM * 4));
  float*          logits= (float*)(ws + alloc((size_t)T_TOK * NEXP * 4));
  int*            idx2  = (int*)(ws + alloc((size_t)T_TOK * 2 * 4));
  float*          w2    = (float*)(ws + alloc((size_t)T_TOK * 2 * 4));
  int*            toks  = (int*)(ws + alloc((size_t)T_TOK * TOPK * 4));
  float*          wts   = (float*)(ws + alloc((size_t)T_TOK * TOPK * 4));
  int*            counts= (int*)(ws + alloc(256));
  int*            cursors=(int*)(ws + alloc(256));
  int*            offs  = (int*)(ws + alloc(256));
  unsigned short* ehb   = (unsigned short*)(ws + alloc((size_t)T_TOK * TOPK * HDIM * 2));

  zero_small_kernel<<<1, 64, 0, stream>>>(counts, cursors);

  const int n4 = T_TOK * DDIM / 4;
  split_x_kernel<<<(n4 + 255) / 256, 256, 0, stream>>>(x, xb, xaug, n4);
  split_w_kernel<<<dim3(DDIM / 32, DDIM / 32), 256, 0, stream>>>(rw1, waug);
  transpose_conv_kernel<<<dim3(HDIM / 32, DDIM / 32, NEXP), 256, 0, stream>>>(ew1, ew1t, DDIM, HDIM);
  transpose_conv_kernel<<<dim3(DDIM / 32, HDIM / 32, NEXP), 256, 0, stream>>>(ew2, ew2t, HDIM, DDIM);

  // router layer 1 (split-bf16, K=3072): rh = silu(x @ rw1 + rb1), near-fp32 accurate
  gemm_mfma<0><<<dim3(T_TOK / 128, DDIM / 128, 1), 256, 0, stream>>>(
      xaug, waug, rb1, rh, nullptr, nullptr, nullptr, nullptr, nullptr, DDIM, KAUG);
  router2_kernel<<<T_TOK / 4, 256, 0, stream>>>(rh, rw2, rb2, logits);
  topk_kernel<<<T_TOK / 256, 256, 0, stream>>>(logits, idx2, w2, counts);
  prefix_kernel<<<1, 64, 0, stream>>>(counts, offs);
  scatter_kernel<<<T_TOK / 256, 256, 0, stream>>>(idx2, w2, offs, cursors, toks, wts);

  // y = x (residual)
  copy_x_kernel<<<(n4 + 255) / 256, 256, 0, stream>>>(x, y, n4);

  // expert layer 1: ehb = silu(gather(xb) @ ew1[e] + eb1[e])  (bf16)
  gemm_mfma<1><<<dim3(T_TOK / 128, HDIM / 128, NEXP), 256, 0, stream>>>(
      xb, ew1t, eb1, nullptr, ehb, toks, nullptr, offs, counts, HDIM, DDIM);
  // expert layer 2: y += w * (ehb @ ew2[e] + eb2[e])
  gemm_mfma<2><<<dim3(T_TOK / 128, DDIM / 128, NEXP), 256, 0, stream>>>(
      ehb, ew2t, eb2, y, nullptr, toks, wts, offs, counts, DDIM, HDIM);
}

// Round 3
// 932.174 us; speedup vs baseline: 1.0319x; 1.0319x over previous
//
#include <hip/hip_runtime.h>
#include <hip/hip_bf16.h>
#include <cstdint>
#include <cstddef>

// Problem constants (B*F tokens)
#define T_TOK 8192
#define DDIM  1024
#define HDIM  2048
#define NEXP  8
#define TOPK  2
#define KAUG  (3 * DDIM)   // split-bf16 router K

typedef short bf16x8 __attribute__((ext_vector_type(8)));
typedef float f32x4  __attribute__((ext_vector_type(4)));

__device__ __forceinline__ unsigned short f2bf(float f) {
  union { float f; unsigned u; } v; v.f = f;
  unsigned r = v.u + 0x7FFFu + ((v.u >> 16) & 1u);
  return (unsigned short)(r >> 16);
}
__device__ __forceinline__ float bf2f(unsigned short h) {
  union { unsigned u; float f; } v; v.u = ((unsigned)h) << 16;
  return v.f;
}
__device__ __forceinline__ float silu_fast(float v) {
  return v / (1.0f + __expf(-v));
}
__device__ __forceinline__ float silu_precise(float v) {
  return v / (1.0f + expf(-v));
}

// async global->LDS, 16B per lane; LDS dest is wave-uniform base + lane*16
__device__ __forceinline__ void gload16(const unsigned short* g, unsigned short* l) {
  __builtin_amdgcn_global_load_lds(
      (const __attribute__((address_space(1))) unsigned int*)g,
      (__attribute__((address_space(3))) unsigned int*)l,
      16, 0, 0);
}

// ---------------- conversion kernels ----------------
// x fp32 -> xaug = [hi | hi | lo] per row (K=3072); hi part doubles as expert A
__global__ void split_x_kernel(const float* __restrict__ in,
                               unsigned short* __restrict__ xaug, int n4) {
  int i = blockIdx.x * blockDim.x + threadIdx.x;
  if (i >= n4) return;
  float4 v = ((const float4*)in)[i];
  int t = i / (DDIM / 4);
  int kc = (i % (DDIM / 4)) * 4;
  float f[4] = {v.x, v.y, v.z, v.w};
  ushort4 hi, lo;
  unsigned short h[4], l[4];
#pragma unroll
  for (int j = 0; j < 4; j++) {
    h[j] = f2bf(f[j]);
    l[j] = f2bf(f[j] - bf2f(h[j]));
  }
  hi.x = h[0]; hi.y = h[1]; hi.z = h[2]; hi.w = h[3];
  lo.x = l[0]; lo.y = l[1]; lo.z = l[2]; lo.w = l[3];
  *(ushort4*)&xaug[(size_t)t * KAUG + kc] = hi;
  *(ushort4*)&xaug[(size_t)t * KAUG + DDIM + kc] = hi;
  *(ushort4*)&xaug[(size_t)t * KAUG + 2 * DDIM + kc] = lo;
}

// rw1 [k][n] fp32 -> waug [n][3072] = [whi | wlo | whi]
__global__ __launch_bounds__(256) void split_w_kernel(
    const float* __restrict__ in, unsigned short* __restrict__ waug) {
  __shared__ float tile[32][33];
  int c0 = blockIdx.x * 32, r0 = blockIdx.y * 32;
  int tx = threadIdx.x & 31, ty = threadIdx.x >> 5;
#pragma unroll
  for (int i = 0; i < 32; i += 8)
    tile[ty + i][tx] = in[(size_t)(r0 + ty + i) * DDIM + (c0 + tx)];
  __syncthreads();
#pragma unroll
  for (int i = 0; i < 32; i += 8) {
    float v = tile[tx][ty + i];          // in[r0+tx][c0+ty+i]
    unsigned short h = f2bf(v);
    unsigned short l = f2bf(v - bf2f(h));
    int n = c0 + ty + i, k = r0 + tx;
    waug[(size_t)n * KAUG + k] = h;
    waug[(size_t)n * KAUG + DDIM + k] = l;
    waug[(size_t)n * KAUG + 2 * DDIM + k] = h;
  }
}

// in: [z][R][C] fp32 -> out: [z][C][R] bf16
__global__ __launch_bounds__(256) void transpose_conv_kernel(
    const float* __restrict__ in, unsigned short* __restrict__ out, int R, int C) {
  __shared__ float tile[32][33];
  const int z = blockIdx.z;
  const float* src = in + (size_t)z * R * C;
  unsigned short* dst = out + (size_t)z * R * C;
  int c0 = blockIdx.x * 32, r0 = blockIdx.y * 32;
  int tx = threadIdx.x & 31, ty = threadIdx.x >> 5;
#pragma unroll
  for (int i = 0; i < 32; i += 8)
    tile[ty + i][tx] = src[(size_t)(r0 + ty + i) * C + (c0 + tx)];
  __syncthreads();
#pragma unroll
  for (int i = 0; i < 32; i += 8)
    dst[(size_t)(c0 + ty + i) * R + (r0 + tx)] = f2bf(tile[tx][ty + i]);
}

__global__ void copy_x_kernel(const float* __restrict__ x,
                              float* __restrict__ y, int n4) {
  int i = blockIdx.x * blockDim.x + threadIdx.x;
  if (i < n4) ((float4*)y)[i] = ((const float4*)x)[i];
}

__global__ void zero_small_kernel(int* __restrict__ counts, int* __restrict__ cursors) {
  int i = threadIdx.x;
  if (i < NEXP) { counts[i] = 0; cursors[i] = 0; }
}

// ---------------- MFMA GEMM (128x128 tile, BK=32, 4 waves) ----------------
// EPI=0: router1  -> outF[p*N+col] = silu(acc + bias[col])          (A dense)
// EPI=1: expert1  -> outBf[(off+p)*N+col] = bf16(silu(acc+bias))    (A gathered by toks)
// EPI=2: expert2  -> atomicAdd(outF[tok*N+col], w*(acc+bias))       (A = packed ehb)
template <int EPI>
__global__ __launch_bounds__(256) void gemm_mfma(
    const unsigned short* __restrict__ Abase,
    const unsigned short* __restrict__ Btbase,  // [z][N][KD] bf16 (pre-transposed)
    const float* __restrict__ bias,             // [z][N]
    float* __restrict__ outF,
    unsigned short* __restrict__ outBf,
    const int* __restrict__ toks, const float* __restrict__ wts,
    const int* __restrict__ offs, const int* __restrict__ cnts,
    int N, int KD, int Astride) {
  const int e = blockIdx.z;
  int ne = 1 << 30, off = 0;
  if (EPI != 0) { ne = cnts[e]; off = offs[e]; }
  const int m0 = blockIdx.x * 128;
  if (EPI != 0 && m0 >= ne) return;
  const int n0 = blockIdx.y * 128;

  const unsigned short* Bt = Btbase + (size_t)e * N * KD;
  const unsigned short* A = (EPI == 2) ? (Abase + (size_t)off * Astride) : Abase;

  __shared__ unsigned short As[128][32];
  __shared__ unsigned short Bs[128][32];

  const int tid  = threadIdx.x;
  const int lane = tid & 63, wid = tid >> 6;
  const int wm = wid >> 1, wn = wid & 1;
  const int quad = lane >> 4, l16 = lane & 15;

  // staging map: thread tid covers LDS byte offset tid*16 (rows tid>>2, col (tid&3)*8)
  const int rowS0 = tid >> 2, rowS1 = (tid >> 2) + 64;
  const int kc0 = (tid & 3) * 8;
  // wave-uniform LDS bases for global_load_lds (lane adds L*16)
  unsigned short* asW0 = &As[0][0] + wid * 512;
  unsigned short* asW1 = asW0 + 2048;
  unsigned short* bsW0 = &Bs[0][0] + wid * 512;
  unsigned short* bsW1 = bsW0 + 2048;

  size_t arow0, arow1;
  if (EPI == 1) {
    int p0 = m0 + rowS0, p1 = m0 + rowS1;
    int t0 = (p0 < ne) ? toks[off + p0] : 0;
    int t1 = (p1 < ne) ? toks[off + p1] : 0;
    arow0 = (size_t)t0 * Astride;
    arow1 = (size_t)t1 * Astride;
  } else if (EPI == 2) {
    int p0 = min(m0 + rowS0, ne - 1);
    int p1 = min(m0 + rowS1, ne - 1);
    arow0 = (size_t)p0 * Astride;
    arow1 = (size_t)p1 * Astride;
  } else {
    arow0 = (size_t)(m0 + rowS0) * Astride;
    arow1 = (size_t)(m0 + rowS1) * Astride;
  }
  const size_t brow0 = (size_t)(n0 + rowS0) * KD;
  const size_t brow1 = (size_t)(n0 + rowS1) * KD;

  f32x4 zf = {0.f, 0.f, 0.f, 0.f};
  f32x4 acc[4][4];
#pragma unroll
  for (int mi = 0; mi < 4; mi++)
#pragma unroll
    for (int ni = 0; ni < 4; ni++) acc[mi][ni] = zf;

  for (int k0 = 0; k0 < KD; k0 += 32) {
    gload16(A + arow0 + k0 + kc0, asW0);
    gload16(A + arow1 + k0 + kc0, asW1);
    gload16(Bt + brow0 + k0 + kc0, bsW0);
    gload16(Bt + brow1 + k0 + kc0, bsW1);
    __syncthreads();
    bf16x8 af[4], bfr[4];
#pragma unroll
    for (int mi = 0; mi < 4; mi++)
      af[mi] = *(const bf16x8*)&As[wm * 64 + mi * 16 + l16][quad * 8];
#pragma unroll
    for (int ni = 0; ni < 4; ni++)
      bfr[ni] = *(const bf16x8*)&Bs[wn * 64 + ni * 16 + l16][quad * 8];
#pragma unroll
    for (int mi = 0; mi < 4; mi++)
#pragma unroll
      for (int ni = 0; ni < 4; ni++)
        acc[mi][ni] = __builtin_amdgcn_mfma_f32_16x16x32_bf16(
            af[mi], bfr[ni], acc[mi][ni], 0, 0, 0);
    __syncthreads();
  }

  // epilogue (C/D layout: col = lane&15, row = quad*4 + r)
#pragma unroll
  for (int mi = 0; mi < 4; mi++) {
    const int prow_base = wm * 64 + mi * 16 + quad * 4;
#pragma unroll
    for (int r = 0; r < 4; r++) {
      const int p = m0 + prow_base + r;
      if (EPI != 0 && p >= ne) continue;
      int tkn = 0; float wgt = 0.f;
      if (EPI == 2) { tkn = toks[off + p]; wgt = wts[off + p]; }
#pragma unroll
      for (int ni = 0; ni < 4; ni++) {
        const int col = n0 + wn * 64 + ni * 16 + l16;
        float v = acc[mi][ni][r] + bias[(size_t)e * N + col];
        if (EPI == 0) {
          outF[(size_t)p * N + col] = silu_precise(v);
        } else if (EPI == 1) {
          outBf[(size_t)(off + p) * N + col] = f2bf(silu_fast(v));
        } else {
          atomicAdd(&outF[(size_t)tkn * N + col], wgt * v);
        }
      }
    }
  }
}

// ---------------- router second layer: logits = rh @ rw2 + rb2 ----------------
__global__ __launch_bounds__(256) void router2_kernel(
    const float* __restrict__ rh, const float* __restrict__ rw2,
    const float* __restrict__ rb2, float* __restrict__ logits) {
  int t = blockIdx.x * 4 + (threadIdx.x >> 6);
  int lane = threadIdx.x & 63;
  const float* row = rh + (size_t)t * DDIM;
  float acc[NEXP];
#pragma unroll
  for (int e = 0; e < NEXP; e++) acc[e] = 0.f;
  for (int k = lane; k < DDIM; k += 64) {
    float v = row[k];
    const float* w = rw2 + (size_t)k * NEXP;
#pragma unroll
    for (int e = 0; e < NEXP; e++) acc[e] += v * w[e];
  }
#pragma unroll
  for (int e = 0; e < NEXP; e++) {
#pragma unroll
    for (int off = 32; off > 0; off >>= 1) acc[e] += __shfl_xor(acc[e], off, 64);
  }
#pragma unroll
  for (int e = 0; e < NEXP; e++)
    if (lane == e) logits[(size_t)t * NEXP + e] = acc[e] + rb2[e];
}

// ---------------- top-2 + softmax + counts ----------------
__global__ void topk_kernel(const float* __restrict__ logits,
                            int* __restrict__ idx2, float* __restrict__ w2arr,
                            int* __restrict__ counts) {
  int t = blockIdx.x * blockDim.x + threadIdx.x;
  if (t >= T_TOK) return;
  float l[NEXP];
#pragma unroll
  for (int e = 0; e < NEXP; e++) l[e] = logits[(size_t)t * NEXP + e];
  int i1 = 0; float v1 = l[0];
#pragma unroll
  for (int e = 1; e < NEXP; e++)
    if (l[e] > v1) { v1 = l[e]; i1 = e; }
  int i2 = -1; float v2 = -3.4e38f;
#pragma unroll
  for (int e = 0; e < NEXP; e++)
    if (e != i1 && l[e] > v2) { v2 = l[e]; i2 = e; }
  float ex = expf(v2 - v1);
  float wa = 1.f / (1.f + ex);
  float wb = ex / (1.f + ex);
  idx2[t * 2] = i1; idx2[t * 2 + 1] = i2;
  w2arr[t * 2] = wa; w2arr[t * 2 + 1] = wb;
  atomicAdd(&counts[i1], 1);
  atomicAdd(&counts[i2], 1);
}

__global__ void prefix_kernel(const int* __restrict__ counts, int* __restrict__ offs) {
  if (threadIdx.x == 0 && blockIdx.x == 0) {
    int s = 0;
    for (int e = 0; e < NEXP; e++) { offs[e] = s; s += counts[e]; }
  }
}

__global__ void scatter_kernel(const int* __restrict__ idx2,
                               const float* __restrict__ w2arr,
                               const int* __restrict__ offs, int* __restrict__ cursors,
                               int* __restrict__ toks, float* __restrict__ wts) {
  int t = blockIdx.x * blockDim.x + threadIdx.x;
  if (t >= T_TOK) return;
#pragma unroll
  for (int j = 0; j < TOPK; j++) {
    int e = idx2[t * 2 + j];
    int pos = atomicAdd(&cursors[e], 1);
    int s = offs[e] + pos;
    toks[s] = t;
    wts[s] = w2arr[t * 2 + j];
  }
}

// ---------------- launch ----------------
extern "C" void kernel_launch(void* const* d_in, const int* in_sizes, int n_in,
                              void* d_out, int out_size, void* d_ws, size_t ws_size,
                              hipStream_t stream) {
  (void)in_sizes; (void)n_in; (void)out_size; (void)ws_size;
  const float* x   = (const float*)d_in[0];
  const float* rw1 = (const float*)d_in[1];
  const float* rb1 = (const float*)d_in[2];
  const float* rw2 = (const float*)d_in[3];
  const float* rb2 = (const float*)d_in[4];
  const float* ew1 = (const float*)d_in[5];
  const float* eb1 = (const float*)d_in[6];
  const float* ew2 = (const float*)d_in[7];
  const float* eb2 = (const float*)d_in[8];
  float* y = (float*)d_out;

  char* ws = (char*)d_ws;
  size_t o = 0;
  auto alloc = [&](size_t bytes) {
    size_t r = o;
    o += (bytes + 255) & ~(size_t)255;
    return r;
  };
  unsigned short* xaug  = (unsigned short*)(ws + alloc((size_t)T_TOK * KAUG * 2));
  unsigned short* waug  = (unsigned short*)(ws + alloc((size_t)DDIM * KAUG * 2));
  unsigned short* ew1t  = (unsigned short*)(ws + alloc((size_t)NEXP * HDIM * DDIM * 2));
  unsigned short* ew2t  = (unsigned short*)(ws + alloc((size_t)NEXP * DDIM * HDIM * 2));
  float*          rh    = (float*)(ws + alloc((size_t)T_TOK * DDIM * 4));
  float*          logits= (float*)(ws + alloc((size_t)T_TOK * NEXP * 4));
  int*            idx2  = (int*)(ws + alloc((size_t)T_TOK * 2 * 4));
  float*          w2    = (float*)(ws + alloc((size_t)T_TOK * 2 * 4));
  int*            toks  = (int*)(ws + alloc((size_t)T_TOK * TOPK * 4));
  float*          wts   = (float*)(ws + alloc((size_t)T_TOK * TOPK * 4));
  int*            counts= (int*)(ws + alloc(256));
  int*            cursors=(int*)(ws + alloc(256));
  int*            offs  = (int*)(ws + alloc(256));
  unsigned short* ehb   = (unsigned short*)(ws + alloc((size_t)T_TOK * TOPK * HDIM * 2));

  zero_small_kernel<<<1, 64, 0, stream>>>(counts, cursors);

  const int n4 = T_TOK * DDIM / 4;
  split_x_kernel<<<(n4 + 255) / 256, 256, 0, stream>>>(x, xaug, n4);
  split_w_kernel<<<dim3(DDIM / 32, DDIM / 32), 256, 0, stream>>>(rw1, waug);
  transpose_conv_kernel<<<dim3(HDIM / 32, DDIM / 32, NEXP), 256, 0, stream>>>(ew1, ew1t, DDIM, HDIM);
  transpose_conv_kernel<<<dim3(DDIM / 32, HDIM / 32, NEXP), 256, 0, stream>>>(ew2, ew2t, HDIM, DDIM);

  // router layer 1 (split-bf16, K=3072): rh = silu(x @ rw1 + rb1), near-fp32 accurate
  gemm_mfma<0><<<dim3(T_TOK / 128, DDIM / 128, 1), 256, 0, stream>>>(
      xaug, waug, rb1, rh, nullptr, nullptr, nullptr, nullptr, nullptr,
      DDIM, KAUG, KAUG);
  router2_kernel<<<T_TOK / 4, 256, 0, stream>>>(rh, rw2, rb2, logits);
  topk_kernel<<<T_TOK / 256, 256, 0, stream>>>(logits, idx2, w2, counts);
  prefix_kernel<<<1, 64, 0, stream>>>(counts, offs);
  scatter_kernel<<<T_TOK / 256, 256, 0, stream>>>(idx2, w2, offs, cursors, toks, wts);

  // y = x (residual)
  copy_x_kernel<<<(n4 + 255) / 256, 256, 0, stream>>>(x, y, n4);

  // expert layer 1: ehb = silu(gather(xaug.hi) @ ew1[e] + eb1[e])  (bf16)
  // grid-x covers worst-case routing skew (up to 16384 rows on one expert)
  gemm_mfma<1><<<dim3(T_TOK * TOPK / 128, HDIM / 128, NEXP), 256, 0, stream>>>(
      xaug, ew1t, eb1, nullptr, ehb, toks, nullptr, offs, counts,
      HDIM, DDIM, KAUG);
  // expert layer 2: y += w * (ehb @ ew2[e] + eb2[e])
  gemm_mfma<2><<<dim3(T_TOK * TOPK / 128, DDIM / 128, NEXP), 256, 0, stream>>>(
      ehb, ew2t, eb2, y, nullptr, toks, wts, offs, counts,
      DDIM, HDIM, HDIM);
}

// Round 4
// 805.600 us; speedup vs baseline: 1.1940x; 1.1571x over previous
//
#include <hip/hip_runtime.h>
#include <hip/hip_bf16.h>
#include <cstdint>
#include <cstddef>

// Problem constants (B*F tokens)
#define T_TOK 8192
#define DDIM  1024
#define HDIM  2048
#define NEXP  8
#define TOPK  2
#define KAUG  (3 * DDIM)   // split-bf16 router K

typedef short bf16x8 __attribute__((ext_vector_type(8)));
typedef float f32x4  __attribute__((ext_vector_type(4)));

__device__ __forceinline__ unsigned short f2bf(float f) {
  union { float f; unsigned u; } v; v.f = f;
  unsigned r = v.u + 0x7FFFu + ((v.u >> 16) & 1u);
  return (unsigned short)(r >> 16);
}
__device__ __forceinline__ float bf2f(unsigned short h) {
  union { unsigned u; float f; } v; v.u = ((unsigned)h) << 16;
  return v.f;
}
__device__ __forceinline__ float silu_fast(float v) {
  return v / (1.0f + __expf(-v));
}
__device__ __forceinline__ float silu_precise(float v) {
  return v / (1.0f + expf(-v));
}

// async global->LDS, 16B per lane; LDS dest is wave-uniform base + lane*16
__device__ __forceinline__ void gload16(const unsigned short* g, unsigned short* l) {
  __builtin_amdgcn_global_load_lds(
      (const __attribute__((address_space(1))) unsigned int*)g,
      (__attribute__((address_space(3))) unsigned int*)l,
      16, 0, 0);
}

// ---------------- conversion kernels ----------------
// x fp32 -> xaug = [hi | hi | lo] per row (K=3072); hi part doubles as expert A
__global__ void split_x_kernel(const float* __restrict__ in,
                               unsigned short* __restrict__ xaug, int n4) {
  int i = blockIdx.x * blockDim.x + threadIdx.x;
  if (i >= n4) return;
  float4 v = ((const float4*)in)[i];
  int t = i / (DDIM / 4);
  int kc = (i % (DDIM / 4)) * 4;
  float f[4] = {v.x, v.y, v.z, v.w};
  ushort4 hi, lo;
  unsigned short h[4], l[4];
#pragma unroll
  for (int j = 0; j < 4; j++) {
    h[j] = f2bf(f[j]);
    l[j] = f2bf(f[j] - bf2f(h[j]));
  }
  hi.x = h[0]; hi.y = h[1]; hi.z = h[2]; hi.w = h[3];
  lo.x = l[0]; lo.y = l[1]; lo.z = l[2]; lo.w = l[3];
  *(ushort4*)&xaug[(size_t)t * KAUG + kc] = hi;
  *(ushort4*)&xaug[(size_t)t * KAUG + DDIM + kc] = hi;
  *(ushort4*)&xaug[(size_t)t * KAUG + 2 * DDIM + kc] = lo;
}

// rw1 [k][n] fp32 -> waug [n][3072] = [whi | wlo | whi]
__global__ __launch_bounds__(256) void split_w_kernel(
    const float* __restrict__ in, unsigned short* __restrict__ waug) {
  __shared__ float tile[32][33];
  int c0 = blockIdx.x * 32, r0 = blockIdx.y * 32;
  int tx = threadIdx.x & 31, ty = threadIdx.x >> 5;
#pragma unroll
  for (int i = 0; i < 32; i += 8)
    tile[ty + i][tx] = in[(size_t)(r0 + ty + i) * DDIM + (c0 + tx)];
  __syncthreads();
#pragma unroll
  for (int i = 0; i < 32; i += 8) {
    float v = tile[tx][ty + i];          // in[r0+tx][c0+ty+i]
    unsigned short h = f2bf(v);
    unsigned short l = f2bf(v - bf2f(h));
    int n = c0 + ty + i, k = r0 + tx;
    waug[(size_t)n * KAUG + k] = h;
    waug[(size_t)n * KAUG + DDIM + k] = l;
    waug[(size_t)n * KAUG + 2 * DDIM + k] = h;
  }
}

// in: [z][R][C] fp32 -> out: [z][C][R] bf16
__global__ __launch_bounds__(256) void transpose_conv_kernel(
    const float* __restrict__ in, unsigned short* __restrict__ out, int R, int C) {
  __shared__ float tile[32][33];
  const int z = blockIdx.z;
  const float* src = in + (size_t)z * R * C;
  unsigned short* dst = out + (size_t)z * R * C;
  int c0 = blockIdx.x * 32, r0 = blockIdx.y * 32;
  int tx = threadIdx.x & 31, ty = threadIdx.x >> 5;
#pragma unroll
  for (int i = 0; i < 32; i += 8)
    tile[ty + i][tx] = src[(size_t)(r0 + ty + i) * C + (c0 + tx)];
  __syncthreads();
#pragma unroll
  for (int i = 0; i < 32; i += 8)
    dst[(size_t)(c0 + ty + i) * R + (r0 + tx)] = f2bf(tile[tx][ty + i]);
}

__global__ void zero_small_kernel(int* __restrict__ counts, int* __restrict__ cursors) {
  int i = threadIdx.x;
  if (i < NEXP) { counts[i] = 0; cursors[i] = 0; }
}

// ---------------- MFMA GEMM (128x128 tile, BK=32 double-buffered, 4 waves) ----
// EPI=0: router1  -> outF[p*N+col] = silu(acc + bias[col])          (A dense)
// EPI=1: expert1  -> outBf[(off+p)*N+col] = bf16(silu(acc+bias))    (A gathered by toks)
// EPI=2: expert2  -> outBf[(off+p)*N+col] = bf16(acc+bias)          (A = packed ehb)
template <int EPI>
__global__ __launch_bounds__(256) void gemm_mfma(
    const unsigned short* __restrict__ Abase,
    const unsigned short* __restrict__ Btbase,  // [z][N][KD] bf16 (pre-transposed)
    const float* __restrict__ bias,             // [z][N]
    float* __restrict__ outF,
    unsigned short* __restrict__ outBf,
    const int* __restrict__ toks,
    const int* __restrict__ offs, const int* __restrict__ cnts,
    int N, int KD, int Astride) {
  const int e = blockIdx.z;
  int ne = T_TOK, off = 0;
  if (EPI != 0) { ne = cnts[e]; off = offs[e]; }
  const int n0 = blockIdx.y * 128;

  const unsigned short* Bt = Btbase + (size_t)e * N * KD;
  const unsigned short* A = (EPI == 2) ? (Abase + (size_t)off * Astride) : Abase;

  __shared__ unsigned short As[2][128][32];
  __shared__ unsigned short Bs[2][128][32];

  const int tid  = threadIdx.x;
  const int lane = tid & 63, wid = tid >> 6;
  const int wm = wid >> 1, wn = wid & 1;
  const int quad = lane >> 4, l16 = lane & 15;

  // staging map: thread tid covers LDS byte offset tid*16 within a buffer
  const int rowS0 = tid >> 2;
  const int kc0 = (tid & 3) * 8;

  const size_t brow0 = (size_t)(n0 + rowS0) * KD;
  const size_t brow1 = brow0 + (size_t)64 * KD;
  const int nIter = KD / 32;
  const int mStride = gridDim.x * 128;

  for (int m0 = blockIdx.x * 128; m0 < ne; m0 += mStride) {
    size_t arow0, arow1;
    if (EPI == 1) {
      int p0 = m0 + rowS0, p1 = m0 + rowS0 + 64;
      int t0 = (p0 < ne) ? toks[off + p0] : 0;
      int t1 = (p1 < ne) ? toks[off + p1] : 0;
      arow0 = (size_t)t0 * Astride;
      arow1 = (size_t)t1 * Astride;
    } else if (EPI == 2) {
      arow0 = (size_t)min(m0 + rowS0, ne - 1) * Astride;
      arow1 = (size_t)min(m0 + rowS0 + 64, ne - 1) * Astride;
    } else {
      arow0 = (size_t)(m0 + rowS0) * Astride;
      arow1 = arow0 + (size_t)64 * Astride;
    }

    f32x4 zf = {0.f, 0.f, 0.f, 0.f};
    f32x4 acc[4][4];
#pragma unroll
    for (int mi = 0; mi < 4; mi++)
#pragma unroll
      for (int ni = 0; ni < 4; ni++) acc[mi][ni] = zf;

    // prologue: stage tile 0 into buffer 0
    {
      unsigned short* a0 = &As[0][0][0] + wid * 512;
      unsigned short* b0 = &Bs[0][0][0] + wid * 512;
      gload16(A + arow0 + kc0, a0);
      gload16(A + arow1 + kc0, a0 + 2048);
      gload16(Bt + brow0 + kc0, b0);
      gload16(Bt + brow1 + kc0, b0 + 2048);
    }

    for (int k = 0; k < nIter; k++) {
      const int cur = k & 1;
      if (k + 1 < nIter) {
        const int nk = (k + 1) * 32;
        unsigned short* a0 = &As[cur ^ 1][0][0] + wid * 512;
        unsigned short* b0 = &Bs[cur ^ 1][0][0] + wid * 512;
        gload16(A + arow0 + nk + kc0, a0);
        gload16(A + arow1 + nk + kc0, a0 + 2048);
        gload16(Bt + brow0 + nk + kc0, b0);
        gload16(Bt + brow1 + nk + kc0, b0 + 2048);
        __builtin_amdgcn_s_waitcnt(0x0F74);  // vmcnt(4): tile k's 4 staging done
      } else {
        __builtin_amdgcn_s_waitcnt(0x0F70);  // vmcnt(0)
      }
      __builtin_amdgcn_s_barrier();
      bf16x8 af[4], bfr[4];
#pragma unroll
      for (int mi = 0; mi < 4; mi++)
        af[mi] = *(const bf16x8*)&As[cur][wm * 64 + mi * 16 + l16][quad * 8];
#pragma unroll
      for (int ni = 0; ni < 4; ni++)
        bfr[ni] = *(const bf16x8*)&Bs[cur][wn * 64 + ni * 16 + l16][quad * 8];
#pragma unroll
      for (int mi = 0; mi < 4; mi++)
#pragma unroll
        for (int ni = 0; ni < 4; ni++)
          acc[mi][ni] = __builtin_amdgcn_mfma_f32_16x16x32_bf16(
              af[mi], bfr[ni], acc[mi][ni], 0, 0, 0);
      __builtin_amdgcn_s_barrier();  // all waves done reading buf[cur]
    }

    // epilogue (C/D layout: col = lane&15, row = quad*4 + r)
#pragma unroll
    for (int mi = 0; mi < 4; mi++) {
      const int prow_base = wm * 64 + mi * 16 + quad * 4;
#pragma unroll
      for (int r = 0; r < 4; r++) {
        const int p = m0 + prow_base + r;
        if (EPI != 0 && p >= ne) continue;
#pragma unroll
        for (int ni = 0; ni < 4; ni++) {
          const int col = n0 + wn * 64 + ni * 16 + l16;
          float v = acc[mi][ni][r] + bias[(size_t)e * N + col];
          if (EPI == 0) {
            outF[(size_t)p * N + col] = silu_precise(v);
          } else if (EPI == 1) {
            outBf[(size_t)(off + p) * N + col] = f2bf(silu_fast(v));
          } else {
            outBf[(size_t)(off + p) * N + col] = f2bf(v);
          }
        }
      }
    }
  }
}

// ---------------- router second layer: logits = rh @ rw2 + rb2 ----------------
__global__ __launch_bounds__(256) void router2_kernel(
    const float* __restrict__ rh, const float* __restrict__ rw2,
    const float* __restrict__ rb2, float* __restrict__ logits) {
  int t = blockIdx.x * 4 + (threadIdx.x >> 6);
  int lane = threadIdx.x & 63;
  const float* row = rh + (size_t)t * DDIM;
  float acc[NEXP];
#pragma unroll
  for (int e = 0; e < NEXP; e++) acc[e] = 0.f;
  for (int k = lane; k < DDIM; k += 64) {
    float v = row[k];
    const float* w = rw2 + (size_t)k * NEXP;
#pragma unroll
    for (int e = 0; e < NEXP; e++) acc[e] += v * w[e];
  }
#pragma unroll
  for (int e = 0; e < NEXP; e++) {
#pragma unroll
    for (int off = 32; off > 0; off >>= 1) acc[e] += __shfl_xor(acc[e], off, 64);
  }
#pragma unroll
  for (int e = 0; e < NEXP; e++)
    if (lane == e) logits[(size_t)t * NEXP + e] = acc[e] + rb2[e];
}

// ---------------- top-2 + softmax + counts ----------------
__global__ void topk_kernel(const float* __restrict__ logits,
                            int* __restrict__ idx2, float* __restrict__ w2arr,
                            int* __restrict__ counts) {
  int t = blockIdx.x * blockDim.x + threadIdx.x;
  if (t >= T_TOK) return;
  float l[NEXP];
#pragma unroll
  for (int e = 0; e < NEXP; e++) l[e] = logits[(size_t)t * NEXP + e];
  int i1 = 0; float v1 = l[0];
#pragma unroll
  for (int e = 1; e < NEXP; e++)
    if (l[e] > v1) { v1 = l[e]; i1 = e; }
  int i2 = -1; float v2 = -3.4e38f;
#pragma unroll
  for (int e = 0; e < NEXP; e++)
    if (e != i1 && l[e] > v2) { v2 = l[e]; i2 = e; }
  float ex = expf(v2 - v1);
  float wa = 1.f / (1.f + ex);
  float wb = ex / (1.f + ex);
  idx2[t * 2] = i1; idx2[t * 2 + 1] = i2;
  w2arr[t * 2] = wa; w2arr[t * 2 + 1] = wb;
  atomicAdd(&counts[i1], 1);
  atomicAdd(&counts[i2], 1);
}

__global__ void prefix_kernel(const int* __restrict__ counts, int* __restrict__ offs) {
  if (threadIdx.x == 0 && blockIdx.x == 0) {
    int s = 0;
    for (int e = 0; e < NEXP; e++) { offs[e] = s; s += counts[e]; }
  }
}

__global__ void scatter_kernel(const int* __restrict__ idx2,
                               const int* __restrict__ offs, int* __restrict__ cursors,
                               int* __restrict__ toks, int* __restrict__ posArr) {
  int t = blockIdx.x * blockDim.x + threadIdx.x;
  if (t >= T_TOK) return;
#pragma unroll
  for (int j = 0; j < TOPK; j++) {
    int e = idx2[t * 2 + j];
    int pos = atomicAdd(&cursors[e], 1);
    int s = offs[e] + pos;
    toks[s] = t;
    posArr[t * 2 + j] = s;
  }
}

// ---------------- final combine: y = x + w0*eo[s0] + w1*eo[s1] ----------------
__global__ __launch_bounds__(256) void combine_kernel(
    const float* __restrict__ x, const unsigned short* __restrict__ eo,
    const int* __restrict__ posArr, const float* __restrict__ w2arr,
    float* __restrict__ y) {
  const int t = blockIdx.x;
  const int d = threadIdx.x * 4;
  const int s0 = posArr[t * 2], s1 = posArr[t * 2 + 1];
  const float w0 = w2arr[t * 2], w1 = w2arr[t * 2 + 1];
  float4 xv = *(const float4*)&x[(size_t)t * DDIM + d];
  ushort4 a = *(const ushort4*)&eo[(size_t)s0 * DDIM + d];
  ushort4 b = *(const ushort4*)&eo[(size_t)s1 * DDIM + d];
  float4 o;
  o.x = xv.x + w0 * bf2f(a.x) + w1 * bf2f(b.x);
  o.y = xv.y + w0 * bf2f(a.y) + w1 * bf2f(b.y);
  o.z = xv.z + w0 * bf2f(a.z) + w1 * bf2f(b.z);
  o.w = xv.w + w0 * bf2f(a.w) + w1 * bf2f(b.w);
  *(float4*)&y[(size_t)t * DDIM + d] = o;
}

// ---------------- launch ----------------
extern "C" void kernel_launch(void* const* d_in, const int* in_sizes, int n_in,
                              void* d_out, int out_size, void* d_ws, size_t ws_size,
                              hipStream_t stream) {
  (void)in_sizes; (void)n_in; (void)out_size; (void)ws_size;
  const float* x   = (const float*)d_in[0];
  const float* rw1 = (const float*)d_in[1];
  const float* rb1 = (const float*)d_in[2];
  const float* rw2 = (const float*)d_in[3];
  const float* rb2 = (const float*)d_in[4];
  const float* ew1 = (const float*)d_in[5];
  const float* eb1 = (const float*)d_in[6];
  const float* ew2 = (const float*)d_in[7];
  const float* eb2 = (const float*)d_in[8];
  float* y = (float*)d_out;

  char* ws = (char*)d_ws;
  size_t o = 0;
  auto alloc = [&](size_t bytes) {
    size_t r = o;
    o += (bytes + 255) & ~(size_t)255;
    return r;
  };
  unsigned short* xaug  = (unsigned short*)(ws + alloc((size_t)T_TOK * KAUG * 2));
  unsigned short* waug  = (unsigned short*)(ws + alloc((size_t)DDIM * KAUG * 2));
  unsigned short* ew1t  = (unsigned short*)(ws + alloc((size_t)NEXP * HDIM * DDIM * 2));
  unsigned short* ew2t  = (unsigned short*)(ws + alloc((size_t)NEXP * DDIM * HDIM * 2));
  float*          rh    = (float*)(ws + alloc((size_t)T_TOK * DDIM * 4));
  float*          logits= (float*)(ws + alloc((size_t)T_TOK * NEXP * 4));
  int*            idx2  = (int*)(ws + alloc((size_t)T_TOK * 2 * 4));
  float*          w2    = (float*)(ws + alloc((size_t)T_TOK * 2 * 4));
  int*            toks  = (int*)(ws + alloc((size_t)T_TOK * TOPK * 4));
  int*            posArr= (int*)(ws + alloc((size_t)T_TOK * TOPK * 4));
  int*            counts= (int*)(ws + alloc(256));
  int*            cursors=(int*)(ws + alloc(256));
  int*            offs  = (int*)(ws + alloc(256));
  unsigned short* ehb   = (unsigned short*)(ws + alloc((size_t)T_TOK * TOPK * HDIM * 2));
  unsigned short* eo    = (unsigned short*)(ws + alloc((size_t)T_TOK * TOPK * DDIM * 2));

  zero_small_kernel<<<1, 64, 0, stream>>>(counts, cursors);

  const int n4 = T_TOK * DDIM / 4;
  split_x_kernel<<<(n4 + 255) / 256, 256, 0, stream>>>(x, xaug, n4);
  split_w_kernel<<<dim3(DDIM / 32, DDIM / 32), 256, 0, stream>>>(rw1, waug);
  transpose_conv_kernel<<<dim3(HDIM / 32, DDIM / 32, NEXP), 256, 0, stream>>>(ew1, ew1t, DDIM, HDIM);
  transpose_conv_kernel<<<dim3(DDIM / 32, HDIM / 32, NEXP), 256, 0, stream>>>(ew2, ew2t, HDIM, DDIM);

  // router layer 1 (split-bf16, K=3072): rh = silu(x @ rw1 + rb1), near-fp32 accurate
  gemm_mfma<0><<<dim3(T_TOK / 128, DDIM / 128, 1), 256, 0, stream>>>(
      xaug, waug, rb1, rh, nullptr, nullptr, nullptr, nullptr,
      DDIM, KAUG, KAUG);
  router2_kernel<<<T_TOK / 4, 256, 0, stream>>>(rh, rw2, rb2, logits);
  topk_kernel<<<T_TOK / 256, 256, 0, stream>>>(logits, idx2, w2, counts);
  prefix_kernel<<<1, 64, 0, stream>>>(counts, offs);
  scatter_kernel<<<T_TOK / 256, 256, 0, stream>>>(idx2, offs, cursors, toks, posArr);

  // expert layer 1: ehb = silu(gather(xaug.hi) @ ew1[e] + eb1[e])  (bf16)
  gemm_mfma<1><<<dim3(16, HDIM / 128, NEXP), 256, 0, stream>>>(
      xaug, ew1t, eb1, nullptr, ehb, toks, offs, counts,
      HDIM, DDIM, KAUG);
  // expert layer 2: eo = ehb @ ew2[e] + eb2[e]  (bf16, packed; weights in combine)
  gemm_mfma<2><<<dim3(16, DDIM / 128, NEXP), 256, 0, stream>>>(
      ehb, ew2t, eb2, nullptr, eo, nullptr, offs, counts,
      DDIM, HDIM, HDIM);
  // y = x + w0*eo[s0] + w1*eo[s1]
  combine_kernel<<<T_TOK, 256, 0, stream>>>(x, eo, posArr, w2, y);
}

// Round 5
// 804.927 us; speedup vs baseline: 1.1950x; 1.0008x over previous
//
#include <hip/hip_runtime.h>
#include <hip/hip_bf16.h>
#include <cstdint>
#include <cstddef>

// Problem constants (B*F tokens)
#define T_TOK 8192
#define DDIM  1024
#define HDIM  2048
#define NEXP  8
#define TOPK  2
#define KAUG  (3 * DDIM)   // split-bf16 router K

typedef short bf16x8 __attribute__((ext_vector_type(8)));
typedef float f32x4  __attribute__((ext_vector_type(4)));

__device__ __forceinline__ unsigned short f2bf(float f) {
  union { float f; unsigned u; } v; v.f = f;
  unsigned r = v.u + 0x7FFFu + ((v.u >> 16) & 1u);
  return (unsigned short)(r >> 16);
}
__device__ __forceinline__ float bf2f(unsigned short h) {
  union { unsigned u; float f; } v; v.u = ((unsigned)h) << 16;
  return v.f;
}
__device__ __forceinline__ float silu_fast(float v) {
  return v / (1.0f + __expf(-v));
}
__device__ __forceinline__ float silu_precise(float v) {
  return v / (1.0f + expf(-v));
}

// async global->LDS, 16B per lane; LDS dest is wave-uniform base + lane*16
__device__ __forceinline__ void gload16(const unsigned short* g, unsigned short* l) {
  __builtin_amdgcn_global_load_lds(
      (const __attribute__((address_space(1))) unsigned int*)g,
      (__attribute__((address_space(3))) unsigned int*)l,
      16, 0, 0);
}

// ---------------- conversion kernels ----------------
// x fp32 -> xaug = [hi | hi | lo] per row (K=3072); hi part doubles as expert A
__global__ void split_x_kernel(const float* __restrict__ in,
                               unsigned short* __restrict__ xaug, int n4) {
  int i = blockIdx.x * blockDim.x + threadIdx.x;
  if (i >= n4) return;
  float4 v = ((const float4*)in)[i];
  int t = i / (DDIM / 4);
  int kc = (i % (DDIM / 4)) * 4;
  float f[4] = {v.x, v.y, v.z, v.w};
  ushort4 hi, lo;
  unsigned short h[4], l[4];
#pragma unroll
  for (int j = 0; j < 4; j++) {
    h[j] = f2bf(f[j]);
    l[j] = f2bf(f[j] - bf2f(h[j]));
  }
  hi.x = h[0]; hi.y = h[1]; hi.z = h[2]; hi.w = h[3];
  lo.x = l[0]; lo.y = l[1]; lo.z = l[2]; lo.w = l[3];
  *(ushort4*)&xaug[(size_t)t * KAUG + kc] = hi;
  *(ushort4*)&xaug[(size_t)t * KAUG + DDIM + kc] = hi;
  *(ushort4*)&xaug[(size_t)t * KAUG + 2 * DDIM + kc] = lo;
}

// rw1 [k][n] fp32 -> waug [n][3072] = [whi | wlo | whi]
__global__ __launch_bounds__(256) void split_w_kernel(
    const float* __restrict__ in, unsigned short* __restrict__ waug) {
  __shared__ float tile[32][33];
  int c0 = blockIdx.x * 32, r0 = blockIdx.y * 32;
  int tx = threadIdx.x & 31, ty = threadIdx.x >> 5;
#pragma unroll
  for (int i = 0; i < 32; i += 8)
    tile[ty + i][tx] = in[(size_t)(r0 + ty + i) * DDIM + (c0 + tx)];
  __syncthreads();
#pragma unroll
  for (int i = 0; i < 32; i += 8) {
    float v = tile[tx][ty + i];          // in[r0+tx][c0+ty+i]
    unsigned short h = f2bf(v);
    unsigned short l = f2bf(v - bf2f(h));
    int n = c0 + ty + i, k = r0 + tx;
    waug[(size_t)n * KAUG + k] = h;
    waug[(size_t)n * KAUG + DDIM + k] = l;
    waug[(size_t)n * KAUG + 2 * DDIM + k] = h;
  }
}

// in: [z][R][C] fp32 -> out: [z][C][R] bf16
__global__ __launch_bounds__(256) void transpose_conv_kernel(
    const float* __restrict__ in, unsigned short* __restrict__ out, int R, int C) {
  __shared__ float tile[32][33];
  const int z = blockIdx.z;
  const float* src = in + (size_t)z * R * C;
  unsigned short* dst = out + (size_t)z * R * C;
  int c0 = blockIdx.x * 32, r0 = blockIdx.y * 32;
  int tx = threadIdx.x & 31, ty = threadIdx.x >> 5;
#pragma unroll
  for (int i = 0; i < 32; i += 8)
    tile[ty + i][tx] = src[(size_t)(r0 + ty + i) * C + (c0 + tx)];
  __syncthreads();
#pragma unroll
  for (int i = 0; i < 32; i += 8)
    dst[(size_t)(c0 + ty + i) * R + (r0 + tx)] = f2bf(tile[tx][ty + i]);
}

__global__ void zero_small_kernel(int* __restrict__ counts, int* __restrict__ cursors) {
  int i = threadIdx.x;
  if (i < NEXP) { counts[i] = 0; cursors[i] = 0; }
}

// ---------------- MFMA GEMM (128x128 tile, BK=32 double-buffered, 4 waves) ----
// 1D grid, XCD-aware decode: e = id % numE (8 experts -> 8 XCDs), then
// n-tile fastest within an expert so consecutive same-XCD blocks reuse the
// same A-tile from that XCD's L2.
// EPI=0: router1  -> outF[p*N+col] = silu(acc + bias[col])          (A dense)
// EPI=1: expert1  -> outBf[(off+p)*N+col] = bf16(silu(acc+bias))    (A gathered by toks)
// EPI=2: expert2  -> outBf[(off+p)*N+col] = bf16(acc+bias)          (A = packed ehb)
template <int EPI>
__global__ __launch_bounds__(256) void gemm_mfma(
    const unsigned short* __restrict__ Abase,
    const unsigned short* __restrict__ Btbase,  // [z][N][KD] bf16 (pre-transposed)
    const float* __restrict__ bias,             // [z][N]
    float* __restrict__ outF,
    unsigned short* __restrict__ outBf,
    const int* __restrict__ toks,
    const int* __restrict__ offs, const int* __restrict__ cnts,
    int N, int KD, int Astride, int numE, int nTiles, int mCap) {
  const int id = blockIdx.x;
  const int e = id % numE;
  const int r = id / numE;
  const int n0 = (r % nTiles) * 128;
  const int mb = r / nTiles;

  int ne = T_TOK, off = 0;
  if (EPI != 0) { ne = cnts[e]; off = offs[e]; }

  const unsigned short* Bt = Btbase + (size_t)e * N * KD;
  const unsigned short* A = (EPI == 2) ? (Abase + (size_t)off * Astride) : Abase;

  __shared__ unsigned short As[2][128][32];
  __shared__ unsigned short Bs[2][128][32];

  const int tid  = threadIdx.x;
  const int lane = tid & 63, wid = tid >> 6;
  const int wm = wid >> 1, wn = wid & 1;
  const int quad = lane >> 4, l16 = lane & 15;

  // staging map: thread tid covers LDS byte offset tid*16 within a buffer
  const int rowS0 = tid >> 2;
  const int kc0 = (tid & 3) * 8;

  const size_t brow0 = (size_t)(n0 + rowS0) * KD;
  const size_t brow1 = brow0 + (size_t)64 * KD;
  const int nIter = KD / 32;
  const int mStride = mCap * 128;

  for (int m0 = mb * 128; m0 < ne; m0 += mStride) {
    size_t arow0, arow1;
    if (EPI == 1) {
      int p0 = m0 + rowS0, p1 = m0 + rowS0 + 64;
      int t0 = (p0 < ne) ? toks[off + p0] : 0;
      int t1 = (p1 < ne) ? toks[off + p1] : 0;
      arow0 = (size_t)t0 * Astride;
      arow1 = (size_t)t1 * Astride;
    } else if (EPI == 2) {
      arow0 = (size_t)min(m0 + rowS0, ne - 1) * Astride;
      arow1 = (size_t)min(m0 + rowS0 + 64, ne - 1) * Astride;
    } else {
      arow0 = (size_t)(m0 + rowS0) * Astride;
      arow1 = arow0 + (size_t)64 * Astride;
    }

    f32x4 zf = {0.f, 0.f, 0.f, 0.f};
    f32x4 acc[4][4];
#pragma unroll
    for (int mi = 0; mi < 4; mi++)
#pragma unroll
      for (int ni = 0; ni < 4; ni++) acc[mi][ni] = zf;

    // prologue: stage tile 0 into buffer 0
    {
      unsigned short* a0 = &As[0][0][0] + wid * 512;
      unsigned short* b0 = &Bs[0][0][0] + wid * 512;
      gload16(A + arow0 + kc0, a0);
      gload16(A + arow1 + kc0, a0 + 2048);
      gload16(Bt + brow0 + kc0, b0);
      gload16(Bt + brow1 + kc0, b0 + 2048);
    }

    for (int k = 0; k < nIter; k++) {
      const int cur = k & 1;
      if (k + 1 < nIter) {
        const int nk = (k + 1) * 32;
        unsigned short* a0 = &As[cur ^ 1][0][0] + wid * 512;
        unsigned short* b0 = &Bs[cur ^ 1][0][0] + wid * 512;
        gload16(A + arow0 + nk + kc0, a0);
        gload16(A + arow1 + nk + kc0, a0 + 2048);
        gload16(Bt + brow0 + nk + kc0, b0);
        gload16(Bt + brow1 + nk + kc0, b0 + 2048);
        __builtin_amdgcn_s_waitcnt(0x0F74);  // vmcnt(4): tile k's 4 staging done
      } else {
        __builtin_amdgcn_s_waitcnt(0x0F70);  // vmcnt(0)
      }
      __builtin_amdgcn_s_barrier();
      bf16x8 af[4], bfr[4];
#pragma unroll
      for (int mi = 0; mi < 4; mi++)
        af[mi] = *(const bf16x8*)&As[cur][wm * 64 + mi * 16 + l16][quad * 8];
#pragma unroll
      for (int ni = 0; ni < 4; ni++)
        bfr[ni] = *(const bf16x8*)&Bs[cur][wn * 64 + ni * 16 + l16][quad * 8];
#pragma unroll
      for (int mi = 0; mi < 4; mi++)
#pragma unroll
        for (int ni = 0; ni < 4; ni++)
          acc[mi][ni] = __builtin_amdgcn_mfma_f32_16x16x32_bf16(
              af[mi], bfr[ni], acc[mi][ni], 0, 0, 0);
      __builtin_amdgcn_s_barrier();  // all waves done reading buf[cur]
    }

    // epilogue (C/D layout: col = lane&15, row = quad*4 + r)
#pragma unroll
    for (int mi = 0; mi < 4; mi++) {
      const int prow_base = wm * 64 + mi * 16 + quad * 4;
#pragma unroll
      for (int rr = 0; rr < 4; rr++) {
        const int p = m0 + prow_base + rr;
        if (EPI != 0 && p >= ne) continue;
#pragma unroll
        for (int ni = 0; ni < 4; ni++) {
          const int col = n0 + wn * 64 + ni * 16 + l16;
          float v = acc[mi][ni][rr] + bias[(size_t)e * N + col];
          if (EPI == 0) {
            outF[(size_t)p * N + col] = silu_precise(v);
          } else if (EPI == 1) {
            outBf[(size_t)(off + p) * N + col] = f2bf(silu_fast(v));
          } else {
            outBf[(size_t)(off + p) * N + col] = f2bf(v);
          }
        }
      }
    }
  }
}

// ---------------- router second layer: logits = rh @ rw2 + rb2 ----------------
__global__ __launch_bounds__(256) void router2_kernel(
    const float* __restrict__ rh, const float* __restrict__ rw2,
    const float* __restrict__ rb2, float* __restrict__ logits) {
  int t = blockIdx.x * 4 + (threadIdx.x >> 6);
  int lane = threadIdx.x & 63;
  const float* row = rh + (size_t)t * DDIM;
  float acc[NEXP];
#pragma unroll
  for (int e = 0; e < NEXP; e++) acc[e] = 0.f;
  for (int k = lane; k < DDIM; k += 64) {
    float v = row[k];
    const float* w = rw2 + (size_t)k * NEXP;
#pragma unroll
    for (int e = 0; e < NEXP; e++) acc[e] += v * w[e];
  }
#pragma unroll
  for (int e = 0; e < NEXP; e++) {
#pragma unroll
    for (int off = 32; off > 0; off >>= 1) acc[e] += __shfl_xor(acc[e], off, 64);
  }
#pragma unroll
  for (int e = 0; e < NEXP; e++)
    if (lane == e) logits[(size_t)t * NEXP + e] = acc[e] + rb2[e];
}

// ---------------- top-2 + softmax + counts ----------------
__global__ void topk_kernel(const float* __restrict__ logits,
                            int* __restrict__ idx2, float* __restrict__ w2arr,
                            int* __restrict__ counts) {
  int t = blockIdx.x * blockDim.x + threadIdx.x;
  if (t >= T_TOK) return;
  float l[NEXP];
#pragma unroll
  for (int e = 0; e < NEXP; e++) l[e] = logits[(size_t)t * NEXP + e];
  int i1 = 0; float v1 = l[0];
#pragma unroll
  for (int e = 1; e < NEXP; e++)
    if (l[e] > v1) { v1 = l[e]; i1 = e; }
  int i2 = -1; float v2 = -3.4e38f;
#pragma unroll
  for (int e = 0; e < NEXP; e++)
    if (e != i1 && l[e] > v2) { v2 = l[e]; i2 = e; }
  float ex = expf(v2 - v1);
  float wa = 1.f / (1.f + ex);
  float wb = ex / (1.f + ex);
  idx2[t * 2] = i1; idx2[t * 2 + 1] = i2;
  w2arr[t * 2] = wa; w2arr[t * 2 + 1] = wb;
  atomicAdd(&counts[i1], 1);
  atomicAdd(&counts[i2], 1);
}

__global__ void prefix_kernel(const int* __restrict__ counts, int* __restrict__ offs) {
  if (threadIdx.x == 0 && blockIdx.x == 0) {
    int s = 0;
    for (int e = 0; e < NEXP; e++) { offs[e] = s; s += counts[e]; }
  }
}

__global__ void scatter_kernel(const int* __restrict__ idx2,
                               const int* __restrict__ offs, int* __restrict__ cursors,
                               int* __restrict__ toks, int* __restrict__ posArr) {
  int t = blockIdx.x * blockDim.x + threadIdx.x;
  if (t >= T_TOK) return;
#pragma unroll
  for (int j = 0; j < TOPK; j++) {
    int e = idx2[t * 2 + j];
    int pos = atomicAdd(&cursors[e], 1);
    int s = offs[e] + pos;
    toks[s] = t;
    posArr[t * 2 + j] = s;
  }
}

// ---------------- final combine: y = x + w0*eo[s0] + w1*eo[s1] ----------------
__global__ __launch_bounds__(256) void combine_kernel(
    const float* __restrict__ x, const unsigned short* __restrict__ eo,
    const int* __restrict__ posArr, const float* __restrict__ w2arr,
    float* __restrict__ y) {
  const int t = blockIdx.x;
  const int d = threadIdx.x * 4;
  const int s0 = posArr[t * 2], s1 = posArr[t * 2 + 1];
  const float w0 = w2arr[t * 2], w1 = w2arr[t * 2 + 1];
  float4 xv = *(const float4*)&x[(size_t)t * DDIM + d];
  ushort4 a = *(const ushort4*)&eo[(size_t)s0 * DDIM + d];
  ushort4 b = *(const ushort4*)&eo[(size_t)s1 * DDIM + d];
  float4 o;
  o.x = xv.x + w0 * bf2f(a.x) + w1 * bf2f(b.x);
  o.y = xv.y + w0 * bf2f(a.y) + w1 * bf2f(b.y);
  o.z = xv.z + w0 * bf2f(a.z) + w1 * bf2f(b.z);
  o.w = xv.w + w0 * bf2f(a.w) + w1 * bf2f(b.w);
  *(float4*)&y[(size_t)t * DDIM + d] = o;
}

// ---------------- launch ----------------
extern "C" void kernel_launch(void* const* d_in, const int* in_sizes, int n_in,
                              void* d_out, int out_size, void* d_ws, size_t ws_size,
                              hipStream_t stream) {
  (void)in_sizes; (void)n_in; (void)out_size; (void)ws_size;
  const float* x   = (const float*)d_in[0];
  const float* rw1 = (const float*)d_in[1];
  const float* rb1 = (const float*)d_in[2];
  const float* rw2 = (const float*)d_in[3];
  const float* rb2 = (const float*)d_in[4];
  const float* ew1 = (const float*)d_in[5];
  const float* eb1 = (const float*)d_in[6];
  const float* ew2 = (const float*)d_in[7];
  const float* eb2 = (const float*)d_in[8];
  float* y = (float*)d_out;

  char* ws = (char*)d_ws;
  size_t o = 0;
  auto alloc = [&](size_t bytes) {
    size_t r = o;
    o += (bytes + 255) & ~(size_t)255;
    return r;
  };
  unsigned short* xaug  = (unsigned short*)(ws + alloc((size_t)T_TOK * KAUG * 2));
  unsigned short* waug  = (unsigned short*)(ws + alloc((size_t)DDIM * KAUG * 2));
  unsigned short* ew1t  = (unsigned short*)(ws + alloc((size_t)NEXP * HDIM * DDIM * 2));
  unsigned short* ew2t  = (unsigned short*)(ws + alloc((size_t)NEXP * DDIM * HDIM * 2));
  float*          rh    = (float*)(ws + alloc((size_t)T_TOK * DDIM * 4));
  float*          logits= (float*)(ws + alloc((size_t)T_TOK * NEXP * 4));
  int*            idx2  = (int*)(ws + alloc((size_t)T_TOK * 2 * 4));
  float*          w2    = (float*)(ws + alloc((size_t)T_TOK * 2 * 4));
  int*            toks  = (int*)(ws + alloc((size_t)T_TOK * TOPK * 4));
  int*            posArr= (int*)(ws + alloc((size_t)T_TOK * TOPK * 4));
  int*            counts= (int*)(ws + alloc(256));
  int*            cursors=(int*)(ws + alloc(256));
  int*            offs  = (int*)(ws + alloc(256));
  unsigned short* ehb   = (unsigned short*)(ws + alloc((size_t)T_TOK * TOPK * HDIM * 2));
  unsigned short* eo    = (unsigned short*)(ws + alloc((size_t)T_TOK * TOPK * DDIM * 2));

  zero_small_kernel<<<1, 64, 0, stream>>>(counts, cursors);

  const int n4 = T_TOK * DDIM / 4;
  split_x_kernel<<<(n4 + 255) / 256, 256, 0, stream>>>(x, xaug, n4);
  split_w_kernel<<<dim3(DDIM / 32, DDIM / 32), 256, 0, stream>>>(rw1, waug);
  transpose_conv_kernel<<<dim3(HDIM / 32, DDIM / 32, NEXP), 256, 0, stream>>>(ew1, ew1t, DDIM, HDIM);
  transpose_conv_kernel<<<dim3(DDIM / 32, HDIM / 32, NEXP), 256, 0, stream>>>(ew2, ew2t, HDIM, DDIM);

  // router layer 1 (split-bf16, K=3072): rh = silu(x @ rw1 + rb1)
  // numE=1, nTiles=8, mCap=64 -> grid 512
  gemm_mfma<0><<<512, 256, 0, stream>>>(
      xaug, waug, rb1, rh, nullptr, nullptr, nullptr, nullptr,
      DDIM, KAUG, KAUG, 1, 8, 64);
  router2_kernel<<<T_TOK / 4, 256, 0, stream>>>(rh, rw2, rb2, logits);
  topk_kernel<<<T_TOK / 256, 256, 0, stream>>>(logits, idx2, w2, counts);
  prefix_kernel<<<1, 64, 0, stream>>>(counts, offs);
  scatter_kernel<<<T_TOK / 256, 256, 0, stream>>>(idx2, offs, cursors, toks, posArr);

  // expert layer 1: ehb = silu(gather(xaug.hi) @ ew1[e] + eb1[e])  (bf16)
  // numE=8 (XCD-aligned), nTiles=16, mCap=16 -> grid 2048
  gemm_mfma<1><<<8 * 16 * 16, 256, 0, stream>>>(
      xaug, ew1t, eb1, nullptr, ehb, toks, offs, counts,
      HDIM, DDIM, KAUG, NEXP, 16, 16);
  // expert layer 2: eo = ehb @ ew2[e] + eb2[e]  (bf16, packed; weights in combine)
  // numE=8, nTiles=8, mCap=32 -> grid 2048
  gemm_mfma<2><<<8 * 8 * 32, 256, 0, stream>>>(
      ehb, ew2t, eb2, nullptr, eo, nullptr, offs, counts,
      DDIM, HDIM, HDIM, NEXP, 8, 32);
  // y = x + w0*eo[s0] + w1*eo[s1]
  combine_kernel<<<T_TOK, 256, 0, stream>>>(x, eo, posArr, w2, y);
}